// Round 3
// baseline (333.895 us; speedup 1.0000x reference)
//
#include <hip/hip_runtime.h>

#define NBLK 256
#define NT 256

// ---------------- grid-wide barrier (sense-reversing, agent scope) ----------------
__device__ __forceinline__ void gridbar(unsigned* cnt, unsigned* gen) {
  __syncthreads();
  if (threadIdx.x == 0) {
    __threadfence();  // release: flush this block's stores to device scope
    unsigned g = __hip_atomic_load(gen, __ATOMIC_RELAXED, __HIP_MEMORY_SCOPE_AGENT);
    unsigned old = __hip_atomic_fetch_add(cnt, 1u, __ATOMIC_ACQ_REL, __HIP_MEMORY_SCOPE_AGENT);
    if (old == NBLK - 1u) {
      __hip_atomic_store(cnt, 0u, __ATOMIC_RELAXED, __HIP_MEMORY_SCOPE_AGENT);
      __hip_atomic_fetch_add(gen, 1u, __ATOMIC_RELEASE, __HIP_MEMORY_SCOPE_AGENT);
    } else {
      while (__hip_atomic_load(gen, __ATOMIC_ACQUIRE, __HIP_MEMORY_SCOPE_AGENT) == g)
        __builtin_amdgcn_s_sleep(2);
    }
    __threadfence();  // acquire: invalidate stale cached lines
  }
  __syncthreads();
}

// ---------------- GEMM phase: tile 256o x 32b, split-K KS=32 ----------------
// P[ks][b][o] = sum_{k in slice} A[b][k] * W[o][k]
template<int KL>
__device__ __forceinline__ void gemm_phase(
    const float* __restrict__ A, const float* __restrict__ W,
    int vgrid, int K, int O,
    float* __restrict__ P, float* __restrict__ Wt, float* __restrict__ At) {
  const int bid = blockIdx.x;
  if (bid < vgrid) {
    constexpr int NG = KL / 4;      // float4 granules per row
    constexpr int PM = NG - 1;      // XOR mask
    const int tid = threadIdx.x;
    const int ks = bid & 31;
    const int obase = (bid >> 5) << 8;
    const int kbeg = ks * KL;

    // stage W [256][KL], granule-XOR swizzled
    #pragma unroll
    for (int t = 0; t < (256 * NG) / NT; ++t) {
      const int s = tid + t * NT;
      const int r = s / NG, p = s % NG;
      const float4 v = *reinterpret_cast<const float4*>(
          &W[(size_t)(obase + r) * K + kbeg + 4 * p]);
      *reinterpret_cast<float4*>(&Wt[r * KL + 4 * (p ^ (r & PM))]) = v;
    }
    // stage A [32][KL] linear
    #pragma unroll
    for (int t = 0; t < (32 * NG + NT - 1) / NT; ++t) {
      const int s = tid + t * NT;
      if (s < 32 * NG) {
        const int r = s / NG, p = s % NG;
        *reinterpret_cast<float4*>(&At[r * KL + 4 * p]) =
            *reinterpret_cast<const float4*>(&A[(size_t)r * K + kbeg + 4 * p]);
      }
    }
    __syncthreads();

    const int to = tid & 63;   // o = obase + to + 64*i
    const int tb = tid >> 6;   // wave-uniform -> A reads broadcast
    float acc[4][8];
    #pragma unroll
    for (int i = 0; i < 4; ++i)
      #pragma unroll
      for (int j = 0; j < 8; ++j) acc[i][j] = 0.f;

    #pragma unroll 2
    for (int gq = 0; gq < NG; ++gq) {
      float4 av[8];
      #pragma unroll
      for (int j = 0; j < 8; ++j)
        av[j] = *reinterpret_cast<const float4*>(&At[(tb * 8 + j) * KL + 4 * gq]);
      #pragma unroll
      for (int i = 0; i < 4; ++i) {
        const int r = to + 64 * i;
        const float4 wv = *reinterpret_cast<const float4*>(
            &Wt[r * KL + 4 * (gq ^ (r & PM))]);
        #pragma unroll
        for (int j = 0; j < 8; ++j) {
          acc[i][j] = fmaf(wv.x, av[j].x, acc[i][j]);
          acc[i][j] = fmaf(wv.y, av[j].y, acc[i][j]);
          acc[i][j] = fmaf(wv.z, av[j].z, acc[i][j]);
          acc[i][j] = fmaf(wv.w, av[j].w, acc[i][j]);
        }
      }
    }

    #pragma unroll
    for (int i = 0; i < 4; ++i)
      #pragma unroll
      for (int j = 0; j < 8; ++j)
        P[((size_t)(ks * 32 + tb * 8 + j)) * O + obase + to + 64 * i] = acc[i][j];
  }
}

// ---------------- reduce partials + bias + relu ----------------
template<int OSH>
__device__ __forceinline__ void reduce_phase(
    const float* __restrict__ P, const float* __restrict__ bias,
    float* __restrict__ C) {
  const int e = blockIdx.x * NT + threadIdx.x;
  if (e < (32 << OSH)) {
    const int o = e & ((1 << OSH) - 1);
    float s = 0.f;
    #pragma unroll
    for (int ks = 0; ks < 32; ++ks)
      s += P[(size_t)((ks * 32) << OSH) + e];
    C[e] = fmaxf(s + bias[o], 0.f);
  }
}

// ---------------- meta phase ----------------
typedef float f2 __attribute__((ext_vector_type(2)));

__device__ __forceinline__ void meta_phase(
    const float* __restrict__ w1, const float* __restrict__ w2, const float* __restrict__ w3,
    const float* __restrict__ a0, const float* __restrict__ a1, const float* __restrict__ a2,
    const float* __restrict__ a3,
    float* __restrict__ n1, float* __restrict__ n2, float* __restrict__ n3,
    const float* __restrict__ mw1, const float* __restrict__ mb1,
    const float* __restrict__ mw2, const float* __restrict__ mb2) {
  const int n1c = (2048 * 1024) / 8;
  const int n2c = (2048 * 2048) / 8;
  const float c2 = mb2[0];
  const f2 zero = (f2){0.f, 0.f};

  for (int it = 0; it < 16; ++it) {
    const int g = it * (NBLK * NT) + blockIdx.x * NT + threadIdx.x;

    const float* W; const float* vin; const float* vout; float* nw;
    int sh, e;
    if (g < n1c)            { W = w1; vin = a0; vout = a1; nw = n1; sh = 10; e = g; }
    else if (g < n1c + n2c) { W = w2; vin = a1; vout = a2; nw = n2; sh = 11; e = g - n1c; }
    else                    { W = w3; vin = a2; vout = a3; nw = n3; sh = 11; e = g - n1c - n2c; }

    const int base = e << 3;
    const int o = base >> sh;
    const int i0 = base & ((1 << sh) - 1);

    f2 wv[4], vv[4];
    {
      float4 t0 = *reinterpret_cast<const float4*>(&W[base]);
      float4 t1 = *reinterpret_cast<const float4*>(&W[base + 4]);
      wv[0] = (f2){t0.x, t0.y}; wv[1] = (f2){t0.z, t0.w};
      wv[2] = (f2){t1.x, t1.y}; wv[3] = (f2){t1.z, t1.w};
      float4 u0 = *reinterpret_cast<const float4*>(&vin[i0]);
      float4 u1 = *reinterpret_cast<const float4*>(&vin[i0 + 4]);
      vv[0] = (f2){u0.x, u0.y}; vv[1] = (f2){u0.z, u0.w};
      vv[2] = (f2){u1.x, u1.y}; vv[3] = (f2){u1.z, u1.w};
    }
    const float vo = vout[o];

    float r[32];
    #pragma unroll
    for (int j = 0; j < 32; ++j)
      r[j] = fmaf(mw1[3 * j + 2], vo, mb1[j]);

    f2 acc[4];
    #pragma unroll
    for (int p = 0; p < 4; ++p) acc[p] = (f2){c2, c2};

    #pragma unroll
    for (int j = 0; j < 32; ++j) {
      const float aj = mw1[3 * j];
      const float bj = mw1[3 * j + 1];
      const float mj = mw2[j];
      const f2 a2v = (f2){aj, aj};
      const f2 b2v = (f2){bj, bj};
      const f2 m2v = (f2){mj, mj};
      const f2 r2v = (f2){r[j], r[j]};
      #pragma unroll
      for (int p = 0; p < 4; ++p) {
#if __has_builtin(__builtin_elementwise_fma) && __has_builtin(__builtin_elementwise_max)
        f2 q = __builtin_elementwise_fma(a2v, vv[p], r2v);
        f2 h = __builtin_elementwise_fma(b2v, wv[p], q);
        h = __builtin_elementwise_max(h, zero);
        acc[p] = __builtin_elementwise_fma(m2v, h, acc[p]);
#else
        f2 h;
        h.x = fmaxf(fmaf(bj, wv[p].x, fmaf(aj, vv[p].x, r[j])), 0.f);
        h.y = fmaxf(fmaf(bj, wv[p].y, fmaf(aj, vv[p].y, r[j])), 0.f);
        acc[p].x = fmaf(mj, h.x, acc[p].x);
        acc[p].y = fmaf(mj, h.y, acc[p].y);
#endif
      }
    }

    float4 o0 = make_float4(acc[0].x, acc[0].y, acc[1].x, acc[1].y);
    float4 o1 = make_float4(acc[2].x, acc[2].y, acc[3].x, acc[3].y);
    *reinterpret_cast<float4*>(&nw[base])     = o0;
    *reinterpret_cast<float4*>(&nw[base + 4]) = o1;
  }
}

// ---------------- the persistent mega-kernel ----------------
__global__ __launch_bounds__(NT, 1) void mega(
    const float* __restrict__ x,
    const float* __restrict__ w1, const float* __restrict__ b1,
    const float* __restrict__ w2, const float* __restrict__ b2,
    const float* __restrict__ w3, const float* __restrict__ b3,
    const float* __restrict__ mw1, const float* __restrict__ mb1,
    const float* __restrict__ mw2, const float* __restrict__ mb2,
    float* __restrict__ outp,   // d_out base
    float* __restrict__ a1, float* __restrict__ a2,
    unsigned* __restrict__ bar) {
  __shared__ float Wt[256 * 64];   // 64 KB
  __shared__ float At[32 * 64];    //  8 KB

  float* n1 = outp + 32 * 1024;
  float* n2 = n1 + 2048 * 1024;
  float* n3 = n2 + 2048 * 2048;
  float* P  = n2;                  // partials live in (dead-until-meta) nw2 region

  unsigned* cnt = bar;
  unsigned* gen = bar + 1;

  // L1: K=1024 -> H=2048, KL=32, 256 vblocks
  gemm_phase<32>(x, w1, 256, 1024, 2048, P, Wt, At);
  gridbar(cnt, gen);
  reduce_phase<11>(P, b1, a1);
  gridbar(cnt, gen);
  // L2: K=2048 -> H=2048, KL=64, 256 vblocks
  gemm_phase<64>(a1, w2, 256, 2048, 2048, P, Wt, At);
  gridbar(cnt, gen);
  reduce_phase<11>(P, b2, a2);
  gridbar(cnt, gen);
  // L3: K=2048 -> O=1024, KL=64, 128 vblocks
  gemm_phase<64>(a2, w3, 128, 2048, 1024, P, Wt, At);
  gridbar(cnt, gen);
  reduce_phase<10>(P, b3, outp);
  gridbar(cnt, gen);
  // meta update for all three layers
  meta_phase(w1, w2, w3, x, a1, a2, outp, n1, n2, n3, mw1, mb1, mw2, mb2);
}

__global__ void init_bar(unsigned* bar) { bar[0] = 0u; bar[1] = 0u; }

extern "C" void kernel_launch(void* const* d_in, const int* in_sizes, int n_in,
                              void* d_out, int out_size, void* d_ws, size_t ws_size,
                              hipStream_t stream) {
  const float* x   = (const float*)d_in[0];
  const float* w1  = (const float*)d_in[1];
  const float* b1  = (const float*)d_in[2];
  const float* w2  = (const float*)d_in[3];
  const float* b2  = (const float*)d_in[4];
  const float* w3  = (const float*)d_in[5];
  const float* b3  = (const float*)d_in[6];
  const float* mw1 = (const float*)d_in[7];
  const float* mb1 = (const float*)d_in[8];
  const float* mw2 = (const float*)d_in[9];
  const float* mb2 = (const float*)d_in[10];

  float* out = (float*)d_out;
  float* ws  = (float*)d_ws;
  unsigned* bar = (unsigned*)ws;          // 2 uints
  float* a1 = ws + 16;                    // 32*2048
  float* a2 = a1 + 32 * 2048;             // 32*2048

  init_bar<<<1, 1, 0, stream>>>(bar);
  mega<<<NBLK, NT, 0, stream>>>(x, w1, b1, w2, b2, w3, b3,
                                mw1, mb1, mw2, mb2, out, a1, a2, bar);
}

// Round 4
// 59.888 us; speedup vs baseline: 5.5753x; 5.5753x over previous
//
#include <hip/hip_runtime.h>

#define NT 256

typedef float f2 __attribute__((ext_vector_type(2)));

// ================= meta body =================
// nw[o,i] = mb2 + sum_j mw2[j]*relu(mw1[3j]*vin[i] + mw1[3j+1]*W[o,i] + mw1[3j+2]*vout[o] + mb1[j])
__device__ __forceinline__ void meta_body(
    int g,
    const float* __restrict__ w1, const float* __restrict__ w2, const float* __restrict__ w3,
    const float* __restrict__ a0, const float* __restrict__ a1, const float* __restrict__ a2,
    const float* __restrict__ a3,
    float* __restrict__ n1, float* __restrict__ n2, float* __restrict__ n3,
    const float* __restrict__ mw1, const float* __restrict__ mb1,
    const float* __restrict__ mw2, const float* __restrict__ mb2) {
  const int n1c = (2048 * 1024) / 8;
  const int n2c = (2048 * 2048) / 8;

  const float* W; const float* vin; const float* vout; float* nw;
  int sh, e;
  if (g < n1c)            { W = w1; vin = a0; vout = a1; nw = n1; sh = 10; e = g; }
  else if (g < n1c + n2c) { W = w2; vin = a1; vout = a2; nw = n2; sh = 11; e = g - n1c; }
  else                    { W = w3; vin = a2; vout = a3; nw = n3; sh = 11; e = g - n1c - n2c; }

  const int base = e << 3;
  const int o = base >> sh;
  const int i0 = base & ((1 << sh) - 1);

  f2 wv[4], vv[4];
  {
    float4 t0 = *reinterpret_cast<const float4*>(&W[base]);
    float4 t1 = *reinterpret_cast<const float4*>(&W[base + 4]);
    wv[0] = (f2){t0.x, t0.y}; wv[1] = (f2){t0.z, t0.w};
    wv[2] = (f2){t1.x, t1.y}; wv[3] = (f2){t1.z, t1.w};
    float4 u0 = *reinterpret_cast<const float4*>(&vin[i0]);
    float4 u1 = *reinterpret_cast<const float4*>(&vin[i0 + 4]);
    vv[0] = (f2){u0.x, u0.y}; vv[1] = (f2){u0.z, u0.w};
    vv[2] = (f2){u1.x, u1.y}; vv[3] = (f2){u1.z, u1.w};
  }
  const float vo = vout[o];
  const float c2 = mb2[0];

  float r[32];
  #pragma unroll
  for (int j = 0; j < 32; ++j)
    r[j] = fmaf(mw1[3 * j + 2], vo, mb1[j]);

  f2 acc[4];
  #pragma unroll
  for (int p = 0; p < 4; ++p) acc[p] = (f2){c2, c2};

  const f2 zero = (f2){0.f, 0.f};
  #pragma unroll
  for (int j = 0; j < 32; ++j) {
    const float aj = mw1[3 * j];
    const float bj = mw1[3 * j + 1];
    const float mj = mw2[j];
    const f2 a2v = (f2){aj, aj};
    const f2 b2v = (f2){bj, bj};
    const f2 m2v = (f2){mj, mj};
    const f2 r2v = (f2){r[j], r[j]};
    #pragma unroll
    for (int p = 0; p < 4; ++p) {
#if __has_builtin(__builtin_elementwise_fma) && __has_builtin(__builtin_elementwise_max)
      f2 q = __builtin_elementwise_fma(a2v, vv[p], r2v);
      f2 h = __builtin_elementwise_fma(b2v, wv[p], q);
      h = __builtin_elementwise_max(h, zero);
      acc[p] = __builtin_elementwise_fma(m2v, h, acc[p]);
#else
      f2 h;
      h.x = fmaxf(fmaf(bj, wv[p].x, fmaf(aj, vv[p].x, r[j])), 0.f);
      h.y = fmaxf(fmaf(bj, wv[p].y, fmaf(aj, vv[p].y, r[j])), 0.f);
      acc[p].x = fmaf(mj, h.x, acc[p].x);
      acc[p].y = fmaf(mj, h.y, acc[p].y);
#endif
    }
  }

  float4 o0 = make_float4(acc[0].x, acc[0].y, acc[1].x, acc[1].y);
  float4 o1 = make_float4(acc[2].x, acc[2].y, acc[3].x, acc[3].y);
  *reinterpret_cast<float4*>(&nw[base])     = o0;
  *reinterpret_cast<float4*>(&nw[base + 4]) = o1;
}

// ================= GEMM body =================
// Tile 128o x 32b, split-K KS=32 (ks = gbid&31), K-slice length KL.
// P[ks][b][o] = sum_{k in slice} A[b][k] * W[o][k]
template<int KL>
__device__ __forceinline__ void gemm_body(
    int gbid, const float* __restrict__ A, const float* __restrict__ W,
    float* __restrict__ P, int K, int O,
    float* __restrict__ Wt, float* __restrict__ At) {
  constexpr int NG = KL / 4;      // float4 granules per row
  constexpr int PM = NG - 1;      // XOR swizzle mask
  const int tid = threadIdx.x;
  const int ks = gbid & 31;
  const int obase = (gbid >> 5) << 7;   // *128
  const int kbeg = ks * KL;

  // stage W tile [128][KL], granule-XOR swizzled
  #pragma unroll
  for (int t = 0; t < (128 * NG) / NT; ++t) {
    const int s = tid + t * NT;
    const int r = s / NG, p = s % NG;
    const float4 v = *reinterpret_cast<const float4*>(
        &W[(size_t)(obase + r) * K + kbeg + 4 * p]);
    *reinterpret_cast<float4*>(&Wt[r * KL + 4 * (p ^ (r & PM))]) = v;
  }
  // stage A tile [32][KL] linear
  #pragma unroll
  for (int t = 0; t < (32 * NG + NT - 1) / NT; ++t) {
    const int s = tid + t * NT;
    if ((32 * NG) % NT == 0 || s < 32 * NG) {
      const int r = s / NG, p = s % NG;
      *reinterpret_cast<float4*>(&At[r * KL + 4 * p]) =
          *reinterpret_cast<const float4*>(&A[(size_t)r * K + kbeg + 4 * p]);
    }
  }
  __syncthreads();

  const int to = tid & 31;          // o = obase + to + 32*i
  const int b0 = (tid >> 5) << 2;   // b = b0 + j (half-wave uniform -> LDS broadcast)
  float acc[4][4];
  #pragma unroll
  for (int i = 0; i < 4; ++i)
    #pragma unroll
    for (int j = 0; j < 4; ++j) acc[i][j] = 0.f;

  #pragma unroll
  for (int gq = 0; gq < NG; ++gq) {
    float4 av[4], wv[4];
    #pragma unroll
    for (int j = 0; j < 4; ++j)
      av[j] = *reinterpret_cast<const float4*>(&At[(b0 + j) * KL + 4 * gq]);
    const int c = 4 * (gq ^ (to & PM));
    #pragma unroll
    for (int i = 0; i < 4; ++i)
      wv[i] = *reinterpret_cast<const float4*>(&Wt[(to + 32 * i) * KL + c]);
    #pragma unroll
    for (int i = 0; i < 4; ++i) {
      #pragma unroll
      for (int j = 0; j < 4; ++j) {
        acc[i][j] = fmaf(wv[i].x, av[j].x, acc[i][j]);
        acc[i][j] = fmaf(wv[i].y, av[j].y, acc[i][j]);
        acc[i][j] = fmaf(wv[i].z, av[j].z, acc[i][j]);
        acc[i][j] = fmaf(wv[i].w, av[j].w, acc[i][j]);
      }
    }
  }

  #pragma unroll
  for (int i = 0; i < 4; ++i)
    #pragma unroll
    for (int j = 0; j < 4; ++j)
      P[(size_t)(ks * 32 + b0 + j) * O + obase + to + 32 * i] = acc[i][j];
}

// ================= combined kernel: gemm blocks + meta blocks =================
template<int KL>
__global__ __launch_bounds__(NT) void combo(
    int nGemm,
    const float* __restrict__ A, const float* __restrict__ W,
    float* __restrict__ P, int K, int O,
    int gbase,
    const float* __restrict__ w1, const float* __restrict__ w2, const float* __restrict__ w3,
    const float* __restrict__ a0, const float* __restrict__ a1, const float* __restrict__ a2,
    const float* __restrict__ a3,
    float* __restrict__ n1, float* __restrict__ n2, float* __restrict__ n3,
    const float* __restrict__ mw1, const float* __restrict__ mb1,
    const float* __restrict__ mw2, const float* __restrict__ mb2) {
  __shared__ float Wt[128 * KL];
  __shared__ float At[32 * KL];
  const int bid = blockIdx.x;
  if (bid < nGemm) {
    gemm_body<KL>(bid, A, W, P, K, O, Wt, At);
  } else {
    const int g = gbase + (bid - nGemm) * NT + threadIdx.x;
    meta_body(g, w1, w2, w3, a0, a1, a2, a3, n1, n2, n3, mw1, mb1, mw2, mb2);
  }
}

// pure meta kernel (no LDS -> best occupancy) for the tail
__global__ __launch_bounds__(NT) void meta_only(
    int gbase,
    const float* __restrict__ w1, const float* __restrict__ w2, const float* __restrict__ w3,
    const float* __restrict__ a0, const float* __restrict__ a1, const float* __restrict__ a2,
    const float* __restrict__ a3,
    float* __restrict__ n1, float* __restrict__ n2, float* __restrict__ n3,
    const float* __restrict__ mw1, const float* __restrict__ mb1,
    const float* __restrict__ mw2, const float* __restrict__ mb2) {
  const int g = gbase + blockIdx.x * NT + threadIdx.x;
  meta_body(g, w1, w2, w3, a0, a1, a2, a3, n1, n2, n3, mw1, mb1, mw2, mb2);
}

// ================= reduce partials + bias + relu (KS=32) =================
template<int OSH>
__global__ __launch_bounds__(NT) void red32(
    const float* __restrict__ P, const float* __restrict__ bias,
    float* __restrict__ C) {
  const int e = blockIdx.x * NT + threadIdx.x;   // e = b*O + o
  const int o = e & ((1 << OSH) - 1);
  float s = 0.f;
  #pragma unroll
  for (int ks = 0; ks < 32; ++ks)
    s += P[((size_t)ks << (5 + OSH)) + e];
  C[e] = fmaxf(s + bias[o], 0.f);
}

extern "C" void kernel_launch(void* const* d_in, const int* in_sizes, int n_in,
                              void* d_out, int out_size, void* d_ws, size_t ws_size,
                              hipStream_t stream) {
  const float* x   = (const float*)d_in[0];
  const float* w1  = (const float*)d_in[1];
  const float* b1  = (const float*)d_in[2];
  const float* w2  = (const float*)d_in[3];
  const float* b2  = (const float*)d_in[4];
  const float* w3  = (const float*)d_in[5];
  const float* b3  = (const float*)d_in[6];
  const float* mw1 = (const float*)d_in[7];
  const float* mb1 = (const float*)d_in[8];
  const float* mw2 = (const float*)d_in[9];
  const float* mb2 = (const float*)d_in[10];

  float* out = (float*)d_out;                 // [32][1024]
  float* n1  = out + 32 * 1024;               // [2048][1024]
  float* n2  = n1 + 2048 * 1024;              // [2048][2048]
  float* n3  = n2 + 2048 * 2048;              // [1024][2048]

  float* ws = (float*)d_ws;
  float* a1 = ws;                             // 32*2048
  float* a2 = ws + 65536;                     // 32*2048
  float* P  = ws + 131072;                    // up to 32*32*2048 floats (8 MB)

  // K1: gemm1 alone. K=1024, O=2048, KS=32, KL=32 -> 16 otiles * 32 = 512 blocks
  combo<32><<<512, NT, 0, stream>>>(512, x, w1, P, 1024, 2048,
      0, w1, w2, w3, x, a1, a2, out, n1, n2, n3, mw1, mb1, mw2, mb2);
  // K2: reduce1 -> a1
  red32<11><<<(32 * 2048) / NT, NT, 0, stream>>>(P, b1, a1);
  // K3: gemm2 (512 blocks, K=2048,O=2048,KL=64) || meta layer-1 (1024 blocks)
  combo<64><<<512 + 1024, NT, 0, stream>>>(512, a1, w2, P, 2048, 2048,
      0, w1, w2, w3, x, a1, a2, out, n1, n2, n3, mw1, mb1, mw2, mb2);
  // K4: reduce2 -> a2
  red32<11><<<(32 * 2048) / NT, NT, 0, stream>>>(P, b2, a2);
  // K5: gemm3 (256 blocks, K=2048,O=1024,KL=64) || meta layer-2 (2048 blocks)
  combo<64><<<256 + 2048, NT, 0, stream>>>(256, a2, w3, P, 2048, 1024,
      262144, w1, w2, w3, x, a1, a2, out, n1, n2, n3, mw1, mb1, mw2, mb2);
  // K6: reduce3 -> out
  red32<10><<<(32 * 1024) / NT, NT, 0, stream>>>(P, b3, out);
  // K7: meta layer-3 tail (1024 blocks)
  meta_only<<<1024, NT, 0, stream>>>(786432, w1, w2, w3, x, a1, a2, out,
                                     n1, n2, n3, mw1, mb1, mw2, mb2);
}